// Round 5
// baseline (1583.082 us; speedup 1.0000x reference)
//
#include <hip/hip_runtime.h>

#define R_STAGES 8
#define H_HEADS  8
#define K_CODES  4096
#define C_DIM    128
#define N_TOK    4096      // B*S
#define FEAT     1024      // H*C
#define HKC      (H_HEADS * K_CODES * C_DIM)   // elems per stage

#define MARGIN   1.2e-2f
#define WCAP     512
#define TMS      260       // tmin row stride in fp16 elems

typedef _Float16 half8  __attribute__((ext_vector_type(8)));
typedef _Float16 half4v __attribute__((ext_vector_type(4)));
typedef _Float16 half2v __attribute__((ext_vector_type(2)));
typedef float    f32x4  __attribute__((ext_vector_type(4)));

#define MFMA16(A, B, C) __builtin_amdgcn_mfma_f32_16x16x32_f16((A), (B), (C), 0, 0, 0)

union H2U { half2v h; int i; };
__device__ __forceinline__ half2v hmin2(half2v a, half2v b) {
    half2v r;
    r[0] = a[0] < b[0] ? a[0] : b[0];
    r[1] = a[1] < b[1] ? a[1] : b[1];
    return r;                                   // v_pk_min_f16
}
__device__ __forceinline__ half2v shfl_xor_h2(half2v v, int m) {
    H2U u; u.h = v; u.i = __shfl_xor(u.i, m); return u.h;
}

// ---------------------------------------------------------------------------
// ws layout (bytes):
//   t    : float    [H][N][C]   @ 0            (16,777,216)
//   ps   : float    [N]         @ 16,777,216   (16,384)
//   cn   : float    [R][H][K]   @ 16,793,600   (1,048,576)
//   cb16 : _Float16             @ 17,842,176   (67,108,864 full / 8,388,608 per-stage)
//   full path needs 84,951,040 B total.
// ---------------------------------------------------------------------------

__global__ void kc_prep(const float* __restrict__ x, float* __restrict__ t,
                        float* __restrict__ ps) {
    int n = blockIdx.x;
    const float* xr = x + (size_t)n * FEAT;

    double ss = 0.0;
    for (int i = threadIdx.x; i < FEAT; i += 256) {
        float v = xr[i];
        ss += (double)v * (double)v;
    }
    for (int off = 32; off > 0; off >>= 1) ss += __shfl_down(ss, off);

    __shared__ double sred[4];
    __shared__ float s_p;
    int wid = threadIdx.x >> 6, lane = threadIdx.x & 63;
    if (lane == 0) sred[wid] = ss;
    __syncthreads();
    if (threadIdx.x == 0) {
        double tot = sred[0] + sred[1] + sred[2] + sred[3];
        float p = (float)sqrt(tot);
        ps[n] = p;
        s_p = p;
    }
    __syncthreads();
    float p = s_p;

    for (int i = threadIdx.x; i < FEAT; i += 256) {
        int c = i & 127;
        float v = xr[(i & ~127) + ((c & 1) << 6) + (c >> 1)];
        size_t o = ((size_t)(i >> 7) * N_TOK + n) * C_DIM + c;
        t[o] = v / p;
    }
}

// Fused fp32->fp16 convert + squared-norm (one pass over cb). One wave/row.
__global__ void kc_cvtn(const float* __restrict__ cb, _Float16* __restrict__ cb16,
                        float* __restrict__ cn) {
    int w = (blockIdx.x << 2) + (threadIdx.x >> 6);
    int lane = threadIdx.x & 63;
    const float* row = cb + (size_t)w * C_DIM;
    float a = row[lane], b = row[lane + 64];
    _Float16* dr = cb16 + (size_t)w * C_DIM;
    dr[lane]      = (_Float16)a;
    dr[lane + 64] = (_Float16)b;
    double s = (double)a * a + (double)b * b;
    for (int off = 32; off > 0; off >>= 1) s += __shfl_down(s, off);
    if (lane == 0) cn[w] = (float)s;
}

// ---------------------------------------------------------------------------
// One residual stage for one (head, 64-token) block. 512 threads = 8 waves,
// each wave scans K/8 = 512 codes (32 tiles of 16) for all 64 tokens.
// Single fp16-MFMA scan; per-(token,tile) mins to LDS; flagged tiles get
// exact fp64 rescoring; then t -= cb[winner].
// ---------------------------------------------------------------------------
__device__ __forceinline__ void stage_body(
    const float* __restrict__ cbh32, const _Float16* __restrict__ cbh16,
    const float* __restrict__ cnh, float* __restrict__ th) {

    __shared__ _Float16 tmin[64 * TMS];     // [tok][tile(256)] fp16 tile-mins
    __shared__ float    rbs[512][5];        // padded stride: bank-safe
    __shared__ float    mtok[64];
    __shared__ int      wl[WCAP];
    __shared__ double   eD[WCAP];
    __shared__ int      eI[WCAP];
    __shared__ int      winner[64];
    __shared__ int      wlCnt;

    const int tid  = threadIdx.x;
    const int w    = tid >> 6;              // wave 0..7
    const int lane = tid & 63;
    const int col  = lane & 15;
    const int rblk = lane >> 4;

    if (tid == 0) wlCnt = 0;

    // loop-invariant token fragments: tf[g][j] = t[tok=g*16+col][k=rblk*8+j*32 ..+8]
    half8 tf[4][4];
#pragma unroll
    for (int g = 0; g < 4; ++g) {
        const float* trow = th + (size_t)(g * 16 + col) * C_DIM;
#pragma unroll
        for (int j = 0; j < 4; ++j) {
            const float* p = trow + j * 32 + rblk * 8;
            f32x4 lo = *(const f32x4*)p;
            f32x4 hi = *(const f32x4*)(p + 4);
            half8 v;
            v[0] = (_Float16)lo[0]; v[1] = (_Float16)lo[1];
            v[2] = (_Float16)lo[2]; v[3] = (_Float16)lo[3];
            v[4] = (_Float16)hi[0]; v[5] = (_Float16)hi[1];
            v[6] = (_Float16)hi[2]; v[7] = (_Float16)hi[3];
            tf[g][j] = v;
        }
    }

    const int kbase = w << 9;               // wave's K-eighth (512 codes)
    const _Float16* cbA = cbh16 + (size_t)(kbase + col) * C_DIM + rblk * 8;
    const float*    cnA = cnh + kbase + (rblk << 2);

    auto loadA = [&](int it, half8* A, f32x4& cv) {
        const _Float16* p = cbA + (size_t)it * (16 * C_DIM);
#pragma unroll
        for (int j = 0; j < 4; ++j) A[j] = *(const half8*)(p + j * 32);
        cv = *(const f32x4*)(cnA + it * 16);
    };

    half2v rb01, rb23;
    rb01[0] = rb01[1] = rb23[0] = rb23[1] = (_Float16)60000.0f;

    auto screen = [&](const half8* A, const f32x4& cv, int wtile) {
        f32x4 a0 = {0.f,0.f,0.f,0.f}, a1 = {0.f,0.f,0.f,0.f};
        f32x4 a2 = {0.f,0.f,0.f,0.f}, a3 = {0.f,0.f,0.f,0.f};
#pragma unroll
        for (int j = 0; j < 4; ++j) {
            a0 = MFMA16(A[j], tf[0][j], a0);
            a1 = MFMA16(A[j], tf[1][j], a1);
            a2 = MFMA16(A[j], tf[2][j], a2);
            a3 = MFMA16(A[j], tf[3][j], a3);
        }
        float m0 = fminf(fminf(cv[0] - 2.f*a0[0], cv[1] - 2.f*a0[1]),
                         fminf(cv[2] - 2.f*a0[2], cv[3] - 2.f*a0[3]));
        float m1 = fminf(fminf(cv[0] - 2.f*a1[0], cv[1] - 2.f*a1[1]),
                         fminf(cv[2] - 2.f*a1[2], cv[3] - 2.f*a1[3]));
        float m2 = fminf(fminf(cv[0] - 2.f*a2[0], cv[1] - 2.f*a2[1]),
                         fminf(cv[2] - 2.f*a2[2], cv[3] - 2.f*a2[3]));
        float m3 = fminf(fminf(cv[0] - 2.f*a3[0], cv[1] - 2.f*a3[1]),
                         fminf(cv[2] - 2.f*a3[2], cv[3] - 2.f*a3[3]));
        half2v p01, p23;
        p01[0] = (_Float16)m0; p01[1] = (_Float16)m1;
        p23[0] = (_Float16)m2; p23[1] = (_Float16)m3;
        // tile min across the 4 rblk lane-groups: packed shuffles (4 DS ops)
        p01 = hmin2(p01, shfl_xor_h2(p01, 16));
        p23 = hmin2(p23, shfl_xor_h2(p23, 16));
        p01 = hmin2(p01, shfl_xor_h2(p01, 32));
        p23 = hmin2(p23, shfl_xor_h2(p23, 32));
        rb01 = hmin2(rb01, p01);
        rb23 = hmin2(rb23, p23);
        if (rblk == 0) {
            tmin[(col)      * TMS + wtile] = p01[0];
            tmin[(16 + col) * TMS + wtile] = p01[1];
            tmin[(32 + col) * TMS + wtile] = p23[0];
            tmin[(48 + col) * TMS + wtile] = p23[1];
        }
    };

    // ---- single scan, 2-slot register double-buffer ----
    {
        half8 A0[4], A1[4];
        f32x4 v0, v1;
        loadA(0, A0, v0); loadA(1, A1, v1);
        const int wbase = w << 5;
#pragma unroll 1
        for (int j = 0; j < 16; ++j) {
            const int b2 = j << 1;
            screen(A0, v0, wbase + b2);
            if (j < 15) loadA(b2 + 2, A0, v0);
            screen(A1, v1, wbase + b2 + 1);
            if (j < 15) loadA(b2 + 3, A1, v1);
        }
    }
    rbs[tid][0] = (float)rb01[0]; rbs[tid][1] = (float)rb01[1];
    rbs[tid][2] = (float)rb23[0]; rbs[tid][3] = (float)rb23[1];
    __syncthreads();

    // ---- per-token screened min ----
    if (tid < 64) {
        const int g = tid >> 4, c2 = tid & 15;
        float m = 3.4e38f;
#pragma unroll
        for (int ww = 0; ww < 8; ++ww) m = fminf(m, rbs[(ww << 6) + c2][g]);
        mtok[tid] = m;
    }
    __syncthreads();

    // ---- build worklist of flagged (token, tile) pairs ----
    {
        const int tok = tid >> 3, q = tid & 7;   // 8 threads/token, 32 tiles each
        const float thr = mtok[tok] + MARGIN;
        const half4v* rowp = (const half4v*)(tmin + tok * TMS + (q << 5));
#pragma unroll 2
        for (int j4 = 0; j4 < 8; ++j4) {
            half4v v = rowp[j4];
#pragma unroll
            for (int e = 0; e < 4; ++e) {
                if ((float)v[e] < thr) {
                    int idx = atomicAdd(&wlCnt, 1);
                    if (idx < WCAP) wl[idx] = (tok << 8) | ((q << 5) + (j4 << 2) + e);
                }
            }
        }
    }
    __syncthreads();

    int E = wlCnt;
    if (E <= WCAP) {
        // ---- fp64 rescore: one 16-lane group per flagged tile (32/batch) ----
        for (int e0 = 0; e0 < E; e0 += 32) {
            const int e = e0 + (tid >> 4);
            double bd = 1e300; int bi = 0x7fffffff;
            if (e < E) {
                const int meta = wl[e];
                const int tok = meta >> 8;
                const int k = ((meta & 255) << 4) + (tid & 15);
                const float* crow = cbh32 + (size_t)k * C_DIM;
                const float* trw  = th + (size_t)tok * C_DIM;
                double cx0=0,cx1=0,cx2=0,cx3=0,d0=0,d1=0,d2=0,d3=0;
#pragma unroll 4
                for (int c = 0; c < C_DIM; c += 4) {
                    double cv0 = crow[c],   tv0 = trw[c];
                    double cv1 = crow[c+1], tv1 = trw[c+1];
                    double cv2 = crow[c+2], tv2 = trw[c+2];
                    double cv3 = crow[c+3], tv3 = trw[c+3];
                    cx0 = fma(cv0,cv0,cx0); d0 = fma(tv0,cv0,d0);
                    cx1 = fma(cv1,cv1,cx1); d1 = fma(tv1,cv1,d1);
                    cx2 = fma(cv2,cv2,cx2); d2 = fma(tv2,cv2,d2);
                    cx3 = fma(cv3,cv3,cx3); d3 = fma(tv3,cv3,d3);
                }
                bd = ((cx0+cx1)+(cx2+cx3)) - 2.0*((d0+d1)+(d2+d3));
                bi = k;
            }
#pragma unroll
            for (int off = 1; off < 16; off <<= 1) {
                double od = __shfl_xor(bd, off);
                int    oi = __shfl_xor(bi, off);
                if (od < bd || (od == bd && oi < bi)) { bd = od; bi = oi; }
            }
            if ((tid & 15) == 0 && e < E) { eD[e] = bd; eI[e] = bi; }
        }
        __syncthreads();
        if (tid < 64) {
            double bd = 1e300; int bi = 0x7fffffff;
            for (int e = 0; e < E; ++e) {
                if ((wl[e] >> 8) == tid) {
                    double d = eD[e]; int i2 = eI[e];
                    if (d < bd || (d == bd && i2 < bi)) { bd = d; bi = i2; }
                }
            }
            winner[tid] = bi;
        }
        __syncthreads();
    } else {
        // ---- overflow fallback (prob ~0): full fp64 scan, all tokens ----
        for (int ot = 0; ot < 64; ++ot) {
            const float* trw = th + (size_t)ot * C_DIM;
            double bd = 1e300; int bi = 0x7fffffff;
            for (int k = tid; k < K_CODES; k += 512) {
                const float* crow = cbh32 + (size_t)k * C_DIM;
                double cx0=0,cx1=0,cx2=0,cx3=0,d0=0,d1=0,d2=0,d3=0;
                for (int c = 0; c < C_DIM; c += 4) {
                    double cv0 = crow[c],   tv0 = trw[c];
                    double cv1 = crow[c+1], tv1 = trw[c+1];
                    double cv2 = crow[c+2], tv2 = trw[c+2];
                    double cv3 = crow[c+3], tv3 = trw[c+3];
                    cx0 = fma(cv0,cv0,cx0); d0 = fma(tv0,cv0,d0);
                    cx1 = fma(cv1,cv1,cx1); d1 = fma(tv1,cv1,d1);
                    cx2 = fma(cv2,cv2,cx2); d2 = fma(tv2,cv2,d2);
                    cx3 = fma(cv3,cv3,cx3); d3 = fma(tv3,cv3,d3);
                }
                double d = ((cx0+cx1)+(cx2+cx3)) - 2.0*((d0+d1)+(d2+d3));
                if (d < bd || (d == bd && k < bi)) { bd = d; bi = k; }
            }
            for (int off = 1; off <= 32; off <<= 1) {
                double od = __shfl_xor(bd, off);
                int    oi = __shfl_xor(bi, off);
                if (od < bd || (od == bd && oi < bi)) { bd = od; bi = oi; }
            }
            if (lane == 0) { eD[w] = bd; eI[w] = bi; }
            __syncthreads();
            if (tid == 0) {
                double b2 = eD[0]; int i2 = eI[0];
                for (int q = 1; q < 8; ++q) {
                    if (eD[q] < b2 || (eD[q] == b2 && eI[q] < i2)) { b2 = eD[q]; i2 = eI[q]; }
                }
                winner[ot] = i2;
            }
            __syncthreads();
        }
    }

    // ---- residual update: t -= cb[winner] (fp32, matches reference) ----
    for (int i = tid; i < 64 * C_DIM; i += 512) {
        const int tok = i >> 7, c = i & 127;
        th[(size_t)tok * C_DIM + c] -= cbh32[(size_t)winner[tok] * C_DIM + c];
    }
    __syncthreads();
}

// All 8 stages in one kernel — residual chain is per-token independent.
__global__ __launch_bounds__(512, 4)
void kc_all(const float* __restrict__ cb32, const _Float16* __restrict__ cb16,
            const float* __restrict__ cn, float* __restrict__ t) {
    const int h  = blockIdx.x & 7;               // XCD-affine head mapping
    const int n0 = (blockIdx.x >> 3) << 6;
    float* th = t + ((size_t)h * N_TOK + n0) * C_DIM;
#pragma unroll 1
    for (int r = 0; r < R_STAGES; ++r) {
        const size_t off = (size_t)(r * H_HEADS + h) * K_CODES;
        stage_body(cb32 + off * C_DIM, cb16 + off * C_DIM, cn + off, th);
    }
}

// Single-stage variant (used when ws can't hold the full fp16 codebook).
__global__ __launch_bounds__(512, 4)
void kc_stage_one(const float* __restrict__ cb32, const _Float16* __restrict__ cb16,
                  const float* __restrict__ cn, float* __restrict__ t) {
    const int h  = blockIdx.x & 7;
    const int n0 = (blockIdx.x >> 3) << 6;
    float* th = t + ((size_t)h * N_TOK + n0) * C_DIM;
    const size_t off = (size_t)h * K_CODES;
    stage_body(cb32 + off * C_DIM, cb16 + off * C_DIM, cn + off, th);
}

__global__ void kc_out(const float* __restrict__ x, const float* __restrict__ t,
                       const float* __restrict__ ps, float* __restrict__ out) {
    int n = blockIdx.x;
    float p = ps[n];
    const float* xr = x + (size_t)n * FEAT;
    for (int i = threadIdx.x; i < FEAT; i += 256) {
        int c = i & 127;
        float v = xr[(i & ~127) + ((c & 1) << 6) + (c >> 1)];
        float t0 = v / p;
        float tf = t[((size_t)(i >> 7) * N_TOK + n) * C_DIM + c];
        out[(size_t)n * FEAT + i] = (t0 - tf) * p;
    }
}

extern "C" void kernel_launch(void* const* d_in, const int* in_sizes, int n_in,
                              void* d_out, int out_size, void* d_ws, size_t ws_size,
                              hipStream_t stream) {
    const float* x  = (const float*)d_in[0];
    const float* cb = (const float*)d_in[1];
    float* out = (float*)d_out;

    float*    t    = (float*)d_ws;
    float*    ps   = (float*)((char*)d_ws + 16777216);
    float*    cn   = (float*)((char*)d_ws + 16793600);
    _Float16* cb16 = (_Float16*)((char*)d_ws + 17842176);

    const bool full = (ws_size >= 84951040ull);   // 17,842,176 + 67,108,864

    kc_prep<<<N_TOK, 256, 0, stream>>>(x, t, ps);

    if (full) {
        kc_cvtn<<<(R_STAGES * H_HEADS * K_CODES) / 4, 256, 0, stream>>>(cb, cb16, cn);
        kc_all<<<H_HEADS * (N_TOK / 64), 512, 0, stream>>>(cb, cb16, cn, t);
    } else {
        for (int r = 0; r < R_STAGES; ++r) {
            kc_cvtn<<<(H_HEADS * K_CODES) / 4, 256, 0, stream>>>(
                cb + (size_t)r * HKC, cb16, cn + (size_t)r * H_HEADS * K_CODES);
            kc_stage_one<<<H_HEADS * (N_TOK / 64), 512, 0, stream>>>(
                cb + (size_t)r * HKC, cb16, cn + (size_t)r * H_HEADS * K_CODES, t);
        }
    }

    kc_out<<<N_TOK, 256, 0, stream>>>(x, t, ps, out);
}

// Round 6
// 1481.646 us; speedup vs baseline: 1.0685x; 1.0685x over previous
//
#include <hip/hip_runtime.h>

#define R_STAGES 8
#define H_HEADS  8
#define K_CODES  4096
#define C_DIM    128
#define N_TOK    4096      // B*S
#define FEAT     1024      // H*C
#define HKC      (H_HEADS * K_CODES * C_DIM)   // elems per stage

#define MARGIN   1.2e-2f
#define WCAP     512
#define TMS      260       // tmin row stride in fp16 elems
#define TPB      32        // tokens per block

typedef _Float16 half8  __attribute__((ext_vector_type(8)));
typedef _Float16 half4v __attribute__((ext_vector_type(4)));
typedef _Float16 half2v __attribute__((ext_vector_type(2)));
typedef float    f32x4  __attribute__((ext_vector_type(4)));
typedef float    f32x2  __attribute__((ext_vector_type(2)));

#define MFMA16(A, B, C) __builtin_amdgcn_mfma_f32_16x16x32_f16((A), (B), (C), 0, 0, 0)

union H2U { half2v h; int i; };
__device__ __forceinline__ half2v hmin2(half2v a, half2v b) {
    half2v r;
    r[0] = a[0] < b[0] ? a[0] : b[0];
    r[1] = a[1] < b[1] ? a[1] : b[1];
    return r;                                   // v_pk_min_f16
}
__device__ __forceinline__ half2v shfl_xor_h2(half2v v, int m) {
    H2U u; u.h = v; u.i = __shfl_xor(u.i, m); return u.h;
}

// ---------------------------------------------------------------------------
// ws layout (bytes):
//   t    : float    [H][N][C]   @ 0            (16,777,216)
//   ps   : float    [N]         @ 16,777,216   (16,384)
//   cn   : float    [R][H][K]   @ 16,793,600   (1,048,576)
//   cb16 : _Float16             @ 17,842,176   (67,108,864 full / 8,388,608 per-stage)
//   full path needs 84,951,040 B total.
// ---------------------------------------------------------------------------

__global__ void kc_prep(const float* __restrict__ x, float* __restrict__ t,
                        float* __restrict__ ps) {
    int n = blockIdx.x;
    const float* xr = x + (size_t)n * FEAT;

    double ss = 0.0;
    for (int i = threadIdx.x; i < FEAT; i += 256) {
        float v = xr[i];
        ss += (double)v * (double)v;
    }
    for (int off = 32; off > 0; off >>= 1) ss += __shfl_down(ss, off);

    __shared__ double sred[4];
    __shared__ float s_p;
    int wid = threadIdx.x >> 6, lane = threadIdx.x & 63;
    if (lane == 0) sred[wid] = ss;
    __syncthreads();
    if (threadIdx.x == 0) {
        double tot = sred[0] + sred[1] + sred[2] + sred[3];
        float p = (float)sqrt(tot);
        ps[n] = p;
        s_p = p;
    }
    __syncthreads();
    float p = s_p;

    for (int i = threadIdx.x; i < FEAT; i += 256) {
        int c = i & 127;
        float v = xr[(i & ~127) + ((c & 1) << 6) + (c >> 1)];
        size_t o = ((size_t)(i >> 7) * N_TOK + n) * C_DIM + c;
        t[o] = v / p;
    }
}

// Fused fp32->fp16 convert + squared-norm (one pass over cb). One wave/row.
__global__ void kc_cvtn(const float* __restrict__ cb, _Float16* __restrict__ cb16,
                        float* __restrict__ cn) {
    int w = (blockIdx.x << 2) + (threadIdx.x >> 6);
    int lane = threadIdx.x & 63;
    const float* row = cb + (size_t)w * C_DIM;
    float a = row[lane], b = row[lane + 64];
    _Float16* dr = cb16 + (size_t)w * C_DIM;
    dr[lane]      = (_Float16)a;
    dr[lane + 64] = (_Float16)b;
    double s = (double)a * a + (double)b * b;
    for (int off = 32; off > 0; off >>= 1) s += __shfl_down(s, off);
    if (lane == 0) cn[w] = (float)s;
}

// ---------------------------------------------------------------------------
// One residual stage for one (head, 32-token) block. 256 threads = 4 waves,
// each wave scans K/4 = 1024 codes (64 tiles of 16) for all 32 tokens.
// Single fp16-MFMA scan; per-(token,tile) mins to LDS; flagged tiles get
// exact fp64 rescoring; then t -= cb[winner].
// VGPR budget (no spill!): tf 32 + A-dbuf 32 + acc/cv 16 + addr ~20 ~= 105.
// ---------------------------------------------------------------------------
__device__ __forceinline__ void stage_body(
    const float* __restrict__ cbh32, const _Float16* __restrict__ cbh16,
    const float* __restrict__ cnh, float* __restrict__ th) {

    __shared__ _Float16 tmin[TPB * TMS];    // [tok][tile(256)] fp16 tile-mins
    __shared__ f32x2    rbs[256];           // per-thread running mins (2 groups)
    __shared__ float    mtok[TPB];
    __shared__ int      wl[WCAP];
    __shared__ double   eD[WCAP];
    __shared__ int      eI[WCAP];
    __shared__ int      winner[TPB];
    __shared__ int      wlCnt;

    const int tid  = threadIdx.x;
    const int w    = tid >> 6;              // wave 0..3
    const int lane = tid & 63;
    const int col  = lane & 15;
    const int rblk = lane >> 4;

    if (tid == 0) wlCnt = 0;

    // loop-invariant token fragments: tf[g][j] = t[tok=g*16+col][k=rblk*8+j*32 ..+8]
    half8 tf[2][4];
#pragma unroll
    for (int g = 0; g < 2; ++g) {
        const float* trow = th + (size_t)(g * 16 + col) * C_DIM;
#pragma unroll
        for (int j = 0; j < 4; ++j) {
            const float* p = trow + j * 32 + rblk * 8;
            f32x4 lo = *(const f32x4*)p;
            f32x4 hi = *(const f32x4*)(p + 4);
            half8 v;
            v[0] = (_Float16)lo[0]; v[1] = (_Float16)lo[1];
            v[2] = (_Float16)lo[2]; v[3] = (_Float16)lo[3];
            v[4] = (_Float16)hi[0]; v[5] = (_Float16)hi[1];
            v[6] = (_Float16)hi[2]; v[7] = (_Float16)hi[3];
            tf[g][j] = v;
        }
    }

    const int kbase = w << 10;              // wave's K-quarter (1024 codes, 64 tiles)
    const _Float16* cbA = cbh16 + (size_t)(kbase + col) * C_DIM + rblk * 8;
    const float*    cnA = cnh + kbase + (rblk << 2);

    auto loadA = [&](int it, half8* A, f32x4& cv) {
        const _Float16* p = cbA + (size_t)it * (16 * C_DIM);
#pragma unroll
        for (int j = 0; j < 4; ++j) A[j] = *(const half8*)(p + j * 32);
        cv = *(const f32x4*)(cnA + it * 16);
    };

    half2v rb;
    rb[0] = rb[1] = (_Float16)60000.0f;

    auto screen = [&](const half8* A, const f32x4& cv, int wtile) {
        f32x4 a0 = {0.f,0.f,0.f,0.f}, a1 = {0.f,0.f,0.f,0.f};
#pragma unroll
        for (int j = 0; j < 4; ++j) {
            a0 = MFMA16(A[j], tf[0][j], a0);
            a1 = MFMA16(A[j], tf[1][j], a1);
        }
        float m0 = fminf(fminf(cv[0] - 2.f*a0[0], cv[1] - 2.f*a0[1]),
                         fminf(cv[2] - 2.f*a0[2], cv[3] - 2.f*a0[3]));
        float m1 = fminf(fminf(cv[0] - 2.f*a1[0], cv[1] - 2.f*a1[1]),
                         fminf(cv[2] - 2.f*a1[2], cv[3] - 2.f*a1[3]));
        half2v p;
        p[0] = (_Float16)m0; p[1] = (_Float16)m1;
        // tile min across the 4 rblk lane-groups: 2 packed shuffles
        p = hmin2(p, shfl_xor_h2(p, 16));
        p = hmin2(p, shfl_xor_h2(p, 32));
        rb = hmin2(rb, p);
        if (rblk == 0) {
            tmin[(col)      * TMS + wtile] = p[0];
            tmin[(16 + col) * TMS + wtile] = p[1];
        }
    };

    // ---- single scan, register double-buffer (depth 2) ----
    {
        half8 X[4], Y[4];
        f32x4 vx, vy;
        loadA(0, X, vx); loadA(1, Y, vy);
        const int wbase = w << 6;
#pragma unroll 1
        for (int j = 0; j < 32; ++j) {
            const int b2 = j << 1;
            screen(X, vx, wbase + b2);
            if (j < 31) loadA(b2 + 2, X, vx);
            screen(Y, vy, wbase + b2 + 1);
            if (j < 31) loadA(b2 + 3, Y, vy);
        }
    }
    {
        f32x2 s; s[0] = (float)rb[0]; s[1] = (float)rb[1];
        rbs[tid] = s;
    }
    __syncthreads();

    // ---- per-token screened min ----
    if (tid < TPB) {
        const int g = tid >> 4, c2 = tid & 15;
        float m = 3.4e38f;
#pragma unroll
        for (int ww = 0; ww < 4; ++ww) m = fminf(m, rbs[(ww << 6) + c2][g]);
        mtok[tid] = m;
    }
    __syncthreads();

    // ---- build worklist of flagged (token, tile) pairs ----
    {
        const int tok = tid >> 3, q = tid & 7;   // 8 threads/token, 32 tiles each
        const float thr = mtok[tok] + MARGIN;
        const half4v* rowp = (const half4v*)(tmin + tok * TMS + (q << 5));
#pragma unroll 2
        for (int j4 = 0; j4 < 8; ++j4) {
            half4v v = rowp[j4];
#pragma unroll
            for (int e = 0; e < 4; ++e) {
                if ((float)v[e] < thr) {
                    int idx = atomicAdd(&wlCnt, 1);
                    if (idx < WCAP) wl[idx] = (tok << 8) | ((q << 5) + (j4 << 2) + e);
                }
            }
        }
    }
    __syncthreads();

    int E = wlCnt;
    if (E <= WCAP) {
        // ---- fp64 rescore: one 16-lane group per flagged tile (16/batch) ----
        for (int e0 = 0; e0 < E; e0 += 16) {
            const int e = e0 + (tid >> 4);
            double bd = 1e300; int bi = 0x7fffffff;
            if (e < E) {
                const int meta = wl[e];
                const int tok = meta >> 8;
                const int k = ((meta & 255) << 4) + (tid & 15);
                const float* crow = cbh32 + (size_t)k * C_DIM;
                const float* trw  = th + (size_t)tok * C_DIM;
                double cx0=0,cx1=0,cx2=0,cx3=0,d0=0,d1=0,d2=0,d3=0;
#pragma unroll 4
                for (int c = 0; c < C_DIM; c += 4) {
                    double cv0 = crow[c],   tv0 = trw[c];
                    double cv1 = crow[c+1], tv1 = trw[c+1];
                    double cv2 = crow[c+2], tv2 = trw[c+2];
                    double cv3 = crow[c+3], tv3 = trw[c+3];
                    cx0 = fma(cv0,cv0,cx0); d0 = fma(tv0,cv0,d0);
                    cx1 = fma(cv1,cv1,cx1); d1 = fma(tv1,cv1,d1);
                    cx2 = fma(cv2,cv2,cx2); d2 = fma(tv2,cv2,d2);
                    cx3 = fma(cv3,cv3,cx3); d3 = fma(tv3,cv3,d3);
                }
                bd = ((cx0+cx1)+(cx2+cx3)) - 2.0*((d0+d1)+(d2+d3));
                bi = k;
            }
#pragma unroll
            for (int off = 1; off < 16; off <<= 1) {
                double od = __shfl_xor(bd, off);
                int    oi = __shfl_xor(bi, off);
                if (od < bd || (od == bd && oi < bi)) { bd = od; bi = oi; }
            }
            if ((tid & 15) == 0 && e < E) { eD[e] = bd; eI[e] = bi; }
        }
        __syncthreads();
        if (tid < TPB) {
            double bd = 1e300; int bi = 0x7fffffff;
            for (int e = 0; e < E; ++e) {
                if ((wl[e] >> 8) == tid) {
                    double d = eD[e]; int i2 = eI[e];
                    if (d < bd || (d == bd && i2 < bi)) { bd = d; bi = i2; }
                }
            }
            winner[tid] = bi;
        }
        __syncthreads();
    } else {
        // ---- overflow fallback (prob ~0): full fp64 scan, all tokens ----
        for (int ot = 0; ot < TPB; ++ot) {
            const float* trw = th + (size_t)ot * C_DIM;
            double bd = 1e300; int bi = 0x7fffffff;
            for (int k = tid; k < K_CODES; k += 256) {
                const float* crow = cbh32 + (size_t)k * C_DIM;
                double cx0=0,cx1=0,cx2=0,cx3=0,d0=0,d1=0,d2=0,d3=0;
                for (int c = 0; c < C_DIM; c += 4) {
                    double cv0 = crow[c],   tv0 = trw[c];
                    double cv1 = crow[c+1], tv1 = trw[c+1];
                    double cv2 = crow[c+2], tv2 = trw[c+2];
                    double cv3 = crow[c+3], tv3 = trw[c+3];
                    cx0 = fma(cv0,cv0,cx0); d0 = fma(tv0,cv0,d0);
                    cx1 = fma(cv1,cv1,cx1); d1 = fma(tv1,cv1,d1);
                    cx2 = fma(cv2,cv2,cx2); d2 = fma(tv2,cv2,d2);
                    cx3 = fma(cv3,cv3,cx3); d3 = fma(tv3,cv3,d3);
                }
                double d = ((cx0+cx1)+(cx2+cx3)) - 2.0*((d0+d1)+(d2+d3));
                if (d < bd || (d == bd && k < bi)) { bd = d; bi = k; }
            }
            for (int off = 1; off <= 32; off <<= 1) {
                double od = __shfl_xor(bd, off);
                int    oi = __shfl_xor(bi, off);
                if (od < bd || (od == bd && oi < bi)) { bd = od; bi = oi; }
            }
            if (lane == 0) { eD[w] = bd; eI[w] = bi; }
            __syncthreads();
            if (tid == 0) {
                double b2 = eD[0]; int i2 = eI[0];
                for (int q = 1; q < 4; ++q) {
                    if (eD[q] < b2 || (eD[q] == b2 && eI[q] < i2)) { b2 = eD[q]; i2 = eI[q]; }
                }
                winner[ot] = i2;
            }
            __syncthreads();
        }
    }

    // ---- residual update: t -= cb[winner] (fp32, matches reference) ----
    for (int i = tid; i < TPB * C_DIM; i += 256) {
        const int tok = i >> 7, c = i & 127;
        th[(size_t)tok * C_DIM + c] -= cbh32[(size_t)winner[tok] * C_DIM + c];
    }
    __syncthreads();
}

// All 8 stages in one kernel — residual chain is per-token independent.
__global__ __launch_bounds__(256, 4)
void kc_all(const float* __restrict__ cb32, const _Float16* __restrict__ cb16,
            const float* __restrict__ cn, float* __restrict__ t) {
    const int h  = blockIdx.x & 7;               // XCD-affine head mapping
    const int n0 = (blockIdx.x >> 3) * TPB;
    float* th = t + ((size_t)h * N_TOK + n0) * C_DIM;
#pragma unroll 1
    for (int r = 0; r < R_STAGES; ++r) {
        const size_t off = (size_t)(r * H_HEADS + h) * K_CODES;
        stage_body(cb32 + off * C_DIM, cb16 + off * C_DIM, cn + off, th);
    }
}

// Single-stage variant (used when ws can't hold the full fp16 codebook).
__global__ __launch_bounds__(256, 4)
void kc_stage_one(const float* __restrict__ cb32, const _Float16* __restrict__ cb16,
                  const float* __restrict__ cn, float* __restrict__ t) {
    const int h  = blockIdx.x & 7;
    const int n0 = (blockIdx.x >> 3) * TPB;
    float* th = t + ((size_t)h * N_TOK + n0) * C_DIM;
    const size_t off = (size_t)h * K_CODES;
    stage_body(cb32 + off * C_DIM, cb16 + off * C_DIM, cn + off, th);
}

__global__ void kc_out(const float* __restrict__ x, const float* __restrict__ t,
                       const float* __restrict__ ps, float* __restrict__ out) {
    int n = blockIdx.x;
    float p = ps[n];
    const float* xr = x + (size_t)n * FEAT;
    for (int i = threadIdx.x; i < FEAT; i += 256) {
        int c = i & 127;
        float v = xr[(i & ~127) + ((c & 1) << 6) + (c >> 1)];
        float t0 = v / p;
        float tf = t[((size_t)(i >> 7) * N_TOK + n) * C_DIM + c];
        out[(size_t)n * FEAT + i] = (t0 - tf) * p;
    }
}

extern "C" void kernel_launch(void* const* d_in, const int* in_sizes, int n_in,
                              void* d_out, int out_size, void* d_ws, size_t ws_size,
                              hipStream_t stream) {
    const float* x  = (const float*)d_in[0];
    const float* cb = (const float*)d_in[1];
    float* out = (float*)d_out;

    float*    t    = (float*)d_ws;
    float*    ps   = (float*)((char*)d_ws + 16777216);
    float*    cn   = (float*)((char*)d_ws + 16793600);
    _Float16* cb16 = (_Float16*)((char*)d_ws + 17842176);

    const bool full = (ws_size >= 84951040ull);   // 17,842,176 + 67,108,864

    kc_prep<<<N_TOK, 256, 0, stream>>>(x, t, ps);

    if (full) {
        kc_cvtn<<<(R_STAGES * H_HEADS * K_CODES) / 4, 256, 0, stream>>>(cb, cb16, cn);
        kc_all<<<H_HEADS * (N_TOK / TPB), 256, 0, stream>>>(cb, cb16, cn, t);
    } else {
        for (int r = 0; r < R_STAGES; ++r) {
            kc_cvtn<<<(H_HEADS * K_CODES) / 4, 256, 0, stream>>>(
                cb + (size_t)r * HKC, cb16, cn + (size_t)r * H_HEADS * K_CODES);
            kc_stage_one<<<H_HEADS * (N_TOK / TPB), 256, 0, stream>>>(
                cb + (size_t)r * HKC, cb16, cn + (size_t)r * H_HEADS * K_CODES, t);
        }
    }

    kc_out<<<N_TOK, 256, 0, stream>>>(x, t, ps, out);
}

// Round 7
// 1312.956 us; speedup vs baseline: 1.2057x; 1.1285x over previous
//
#include <hip/hip_runtime.h>

#define R_STAGES 8
#define H_HEADS  8
#define K_CODES  4096
#define C_DIM    128
#define N_TOK    4096      // B*S
#define FEAT     1024      // H*C
#define HKC      (H_HEADS * K_CODES * C_DIM)   // elems per stage

#define MARGIN   1.2e-2f
#define WCAP     384
#define TMS      132       // tmin row stride (128 tiles-of-32 + pad), fp16 elems

typedef _Float16 half8  __attribute__((ext_vector_type(8)));
typedef _Float16 half4v __attribute__((ext_vector_type(4)));
typedef _Float16 half2v __attribute__((ext_vector_type(2)));
typedef float    f32x4  __attribute__((ext_vector_type(4)));

#define MFMA16(A, B, C) __builtin_amdgcn_mfma_f32_16x16x32_f16((A), (B), (C), 0, 0, 0)

// counted vmem wait (T4): never drain to 0 in the steady-state loop
#define WAITVM(N) do { asm volatile("s_waitcnt vmcnt(" #N ")" ::: "memory"); \
                       __builtin_amdgcn_sched_barrier(0); } while (0)

union H2U { half2v h; int i; };
__device__ __forceinline__ half2v hmin2(half2v a, half2v b) {
    half2v r;
    r[0] = a[0] < b[0] ? a[0] : b[0];
    r[1] = a[1] < b[1] ? a[1] : b[1];
    return r;                                   // v_pk_min_f16
}
__device__ __forceinline__ half2v shfl_xor_h2(half2v v, int m) {
    H2U u; u.h = v; u.i = __shfl_xor(u.i, m); return u.h;
}

__device__ __forceinline__ void glds16(const _Float16* g, _Float16* l) {
    __builtin_amdgcn_global_load_lds(
        (const __attribute__((address_space(1))) void*)g,
        (__attribute__((address_space(3))) void*)l, 16, 0, 0);
}

// ---------------------------------------------------------------------------
// ws layout (bytes):
//   t    : float    [H][N][C]   @ 0            (16,777,216)
//   ps   : float    [N]         @ 16,777,216   (16,384)
//   cn   : float    [R][H][K]   @ 16,793,600   (1,048,576)
//   cb16 : _Float16             @ 17,842,176   (67,108,864 full / 8,388,608 per-stage)
//   full path needs 84,951,040 B total.
// ---------------------------------------------------------------------------

__global__ void kc_prep(const float* __restrict__ x, float* __restrict__ t,
                        float* __restrict__ ps) {
    int n = blockIdx.x;
    const float* xr = x + (size_t)n * FEAT;

    double ss = 0.0;
    for (int i = threadIdx.x; i < FEAT; i += 256) {
        float v = xr[i];
        ss += (double)v * (double)v;
    }
    for (int off = 32; off > 0; off >>= 1) ss += __shfl_down(ss, off);

    __shared__ double sred[4];
    __shared__ float s_p;
    int wid = threadIdx.x >> 6, lane = threadIdx.x & 63;
    if (lane == 0) sred[wid] = ss;
    __syncthreads();
    if (threadIdx.x == 0) {
        double tot = sred[0] + sred[1] + sred[2] + sred[3];
        float p = (float)sqrt(tot);
        ps[n] = p;
        s_p = p;
    }
    __syncthreads();
    float p = s_p;

    for (int i = threadIdx.x; i < FEAT; i += 256) {
        int c = i & 127;
        float v = xr[(i & ~127) + ((c & 1) << 6) + (c >> 1)];
        size_t o = ((size_t)(i >> 7) * N_TOK + n) * C_DIM + c;
        t[o] = v / p;
    }
}

// Fused fp32->fp16 convert + squared-norm (one pass over cb). One wave/row.
__global__ void kc_cvtn(const float* __restrict__ cb, _Float16* __restrict__ cb16,
                        float* __restrict__ cn) {
    int w = (blockIdx.x << 2) + (threadIdx.x >> 6);
    int lane = threadIdx.x & 63;
    const float* row = cb + (size_t)w * C_DIM;
    float a = row[lane], b = row[lane + 64];
    _Float16* dr = cb16 + (size_t)w * C_DIM;
    dr[lane]      = (_Float16)a;
    dr[lane + 64] = (_Float16)b;
    double s = (double)a * a + (double)b * b;
    for (int off = 32; off > 0; off >>= 1) s += __shfl_down(s, off);
    if (lane == 0) cn[w] = (float)s;
}

// ---------------------------------------------------------------------------
// One residual stage, one (head, 64-token) block. 256 threads = 4 waves, each
// wave scans K/4 = 1024 codes as 64 tiles of 16 codes. Codebook tiles are
// staged global->LDS via global_load_lds into a wave-private 3-buffer ring
// with counted vmcnt(5) waits; the LDS source addresses are pre-swizzled
// (x ^= ((x>>8&7)<<4)) so the swizzled ds_read_b128 fragment reads are
// bank-conflict-free. t-fragments live in VGPRs (64). Single scan records
// per-(token, 32-code-tile) fp16 mins; flagged tiles get exact fp64 rescore.
// ---------------------------------------------------------------------------
__device__ __forceinline__ void stage_body(
    const float* __restrict__ cbh32, const _Float16* __restrict__ cbh16,
    const float* __restrict__ cnh, float* __restrict__ th) {

    __shared__ __align__(16) _Float16 tiles[4][3][2048];  // 49,152 B ring bufs
    __shared__ __align__(16) _Float16 tmin[64 * TMS];     // 16,896 B tile-mins
    __shared__ float    rbs[256][5];                      //  5,120 B
    __shared__ float    mtok[64];
    __shared__ int      wl[WCAP];
    __shared__ double   eD[WCAP];
    __shared__ int      eI[WCAP];
    __shared__ int      winner[64];
    __shared__ int      wlCnt;

    const int tid  = threadIdx.x;
    const int w    = tid >> 6;              // wave 0..3
    const int lane = tid & 63;
    const int col  = lane & 15;
    const int rblk = lane >> 4;

    if (tid == 0) wlCnt = 0;

    // loop-invariant token fragments: tf[g][j] = t[tok=g*16+col][k=rblk*8+j*32 ..+8]
    half8 tf[4][4];
#pragma unroll
    for (int g = 0; g < 4; ++g) {
        const float* trow = th + (size_t)(g * 16 + col) * C_DIM;
#pragma unroll
        for (int j = 0; j < 4; ++j) {
            const float* p = trow + j * 32 + rblk * 8;
            f32x4 lo = *(const f32x4*)p;
            f32x4 hi = *(const f32x4*)(p + 4);
            half8 v;
            v[0] = (_Float16)lo[0]; v[1] = (_Float16)lo[1];
            v[2] = (_Float16)lo[2]; v[3] = (_Float16)lo[3];
            v[4] = (_Float16)hi[0]; v[5] = (_Float16)hi[1];
            v[6] = (_Float16)hi[2]; v[7] = (_Float16)hi[3];
            tf[g][j] = v;
        }
    }

    const int kbase = w << 10;              // wave's K-quarter (1024 codes)
    const char* cbbase = (const char*)cbh16 + (size_t)kbase * 256;

    // stage tile 'it' (16 codes = 4096 B) into ring buffer it%3.
    // Source pre-swizzled so swizzled LDS reads are conflict-free (G21).
    auto stageT = [&](int it) {
        const char* gt = cbbase + (size_t)it * 4096;
        _Float16* lb = tiles[w][it % 3];
#pragma unroll
        for (int c4 = 0; c4 < 4; ++c4) {
            int xx = (lane << 4) + (c4 << 10);
            int src = xx ^ (((xx >> 8) & 7) << 4);
            glds16((const _Float16*)(gt + src), lb + (c4 << 9));
        }
    };

    half2v rb01, rb23;
    rb01[0] = rb01[1] = rb23[0] = rb23[1] = (_Float16)60000.0f;

    // screen tile 'it' from LDS; returns packed per-group tile-of-16 mins
    auto computeT = [&](int it, const f32x4& cv, half2v& p01, half2v& p23) {
        const _Float16* bp = tiles[w][it % 3];
        const int swz  = (col & 7) << 4;
        const int base = (col << 8) + (rblk << 4);   // bytes
        half8 A[4];
#pragma unroll
        for (int j = 0; j < 4; ++j)
            A[j] = *(const half8*)(bp + (((base + (j << 6)) ^ swz) >> 1));
        f32x4 a0 = {0.f,0.f,0.f,0.f}, a1 = {0.f,0.f,0.f,0.f};
        f32x4 a2 = {0.f,0.f,0.f,0.f}, a3 = {0.f,0.f,0.f,0.f};
#pragma unroll
        for (int j = 0; j < 4; ++j) {
            a0 = MFMA16(A[j], tf[0][j], a0);
            a1 = MFMA16(A[j], tf[1][j], a1);
            a2 = MFMA16(A[j], tf[2][j], a2);
            a3 = MFMA16(A[j], tf[3][j], a3);
        }
        float m0 = fminf(fminf(cv[0] - 2.f*a0[0], cv[1] - 2.f*a0[1]),
                         fminf(cv[2] - 2.f*a0[2], cv[3] - 2.f*a0[3]));
        float m1 = fminf(fminf(cv[0] - 2.f*a1[0], cv[1] - 2.f*a1[1]),
                         fminf(cv[2] - 2.f*a1[2], cv[3] - 2.f*a1[3]));
        float m2 = fminf(fminf(cv[0] - 2.f*a2[0], cv[1] - 2.f*a2[1]),
                         fminf(cv[2] - 2.f*a2[2], cv[3] - 2.f*a2[3]));
        float m3 = fminf(fminf(cv[0] - 2.f*a3[0], cv[1] - 2.f*a3[1]),
                         fminf(cv[2] - 2.f*a3[2], cv[3] - 2.f*a3[3]));
        half2v s01, s23;
        s01[0] = (_Float16)m0; s01[1] = (_Float16)m1;
        s23[0] = (_Float16)m2; s23[1] = (_Float16)m3;
        s01 = hmin2(s01, shfl_xor_h2(s01, 16));
        s23 = hmin2(s23, shfl_xor_h2(s23, 16));
        s01 = hmin2(s01, shfl_xor_h2(s01, 32));
        s23 = hmin2(s23, shfl_xor_h2(s23, 32));
        rb01 = hmin2(rb01, s01);
        rb23 = hmin2(rb23, s23);
        p01 = s01; p23 = s23;
    };

    auto cnld = [&](int it) -> f32x4 {
        return *(const f32x4*)(cnh + kbase + (it << 4) + (rblk << 2));
    };

    auto tminW = [&](int jj, half2v q01, half2v q23) {
        if (rblk == 0) {
            const int wt = (w << 5) + jj;
            tmin[(col)      * TMS + wt] = q01[0];
            tmin[(16 + col) * TMS + wt] = q01[1];
            tmin[(32 + col) * TMS + wt] = q23[0];
            tmin[(48 + col) * TMS + wt] = q23[1];
        }
    };

    // ---- single scan over 64 tiles, LDS 3-buffer ring, counted vmcnt ----
    {
        f32x4 cvA = cnld(0), cvB = cnld(1);
        stageT(0); stageT(1);
        half2v p01a, p23a, p01b, p23b;
#pragma unroll 1
        for (int jj = 0; jj < 31; ++jj) {
            const int i0 = jj << 1, i1 = i0 + 1;
            WAITVM(5);                       // tile i0 staged; i0+1 in flight
            f32x4 cvN0 = cnld(i0 + 2);
            stageT(i0 + 2);
            computeT(i0, cvA, p01a, p23a);
            cvA = cvN0;
            WAITVM(5);                       // tile i1 staged; i1+1 in flight
            f32x4 cvN1 = cnld(i1 + 2);
            stageT(i1 + 2);
            computeT(i1, cvB, p01b, p23b);
            cvB = cvN1;
            tminW(jj, hmin2(p01a, p01b), hmin2(p23a, p23b));
        }
        WAITVM(5);
        computeT(62, cvA, p01a, p23a);
        WAITVM(0);
        computeT(63, cvB, p01b, p23b);
        tminW(31, hmin2(p01a, p01b), hmin2(p23a, p23b));
    }
    rbs[tid][0] = (float)rb01[0]; rbs[tid][1] = (float)rb01[1];
    rbs[tid][2] = (float)rb23[0]; rbs[tid][3] = (float)rb23[1];
    __syncthreads();

    // ---- per-token screened min ----
    if (tid < 64) {
        const int g = tid >> 4, c2 = tid & 15;
        float m = 3.4e38f;
#pragma unroll
        for (int ww = 0; ww < 4; ++ww) m = fminf(m, rbs[(ww << 6) + c2][g]);
        mtok[tid] = m;
    }
    __syncthreads();

    // ---- flag (token, 32-code-tile) pairs within MARGIN of token min ----
    {
        const int tok = tid >> 2, q = tid & 3;   // 4 threads/token, 32 tiles each
        const float thr = mtok[tok] + MARGIN;
        const half4v* rowp = (const half4v*)(tmin + tok * TMS + (q << 5));
#pragma unroll 2
        for (int j4 = 0; j4 < 8; ++j4) {
            half4v v = rowp[j4];
#pragma unroll
            for (int e = 0; e < 4; ++e) {
                if ((float)v[e] < thr) {
                    int idx = atomicAdd(&wlCnt, 1);
                    if (idx < WCAP) wl[idx] = (tok << 8) | ((q << 5) + (j4 << 2) + e);
                }
            }
        }
    }
    __syncthreads();

    int E = wlCnt;
    if (E <= WCAP) {
        // ---- fp64 rescore: one 32-lane group per flagged 32-code tile ----
        for (int e0 = 0; e0 < E; e0 += 8) {
            const int e = e0 + (tid >> 5);
            double bd = 1e300; int bi = 0x7fffffff;
            if (e < E) {
                const int meta = wl[e];
                const int tok = meta >> 8;
                const int k = ((meta & 255) << 5) + (tid & 31);
                const float* crow = cbh32 + (size_t)k * C_DIM;
                const float* trw  = th + (size_t)tok * C_DIM;
                double cxa = 0, cxb = 0, da = 0, db = 0;
#pragma unroll 4
                for (int c = 0; c < C_DIM; c += 2) {
                    double cv0 = crow[c],     tv0 = trw[c];
                    double cv1 = crow[c + 1], tv1 = trw[c + 1];
                    cxa = fma(cv0, cv0, cxa); da = fma(tv0, cv0, da);
                    cxb = fma(cv1, cv1, cxb); db = fma(tv1, cv1, db);
                }
                bd = (cxa + cxb) - 2.0 * (da + db);
                bi = k;
            }
#pragma unroll
            for (int off = 1; off < 32; off <<= 1) {
                double od = __shfl_xor(bd, off);
                int    oi = __shfl_xor(bi, off);
                if (od < bd || (od == bd && oi < bi)) { bd = od; bi = oi; }
            }
            if ((tid & 31) == 0 && e < E) { eD[e] = bd; eI[e] = bi; }
        }
        __syncthreads();
        if (tid < 64) {
            double bd = 1e300; int bi = 0x7fffffff;
            for (int e = 0; e < E; ++e) {
                if ((wl[e] >> 8) == tid) {
                    double d = eD[e]; int i2 = eI[e];
                    if (d < bd || (d == bd && i2 < bi)) { bd = d; bi = i2; }
                }
            }
            winner[tid] = bi;
        }
        __syncthreads();
    } else {
        // ---- overflow fallback (prob ~0): full fp64 scan, all tokens ----
        for (int ot = 0; ot < 64; ++ot) {
            const float* trw = th + (size_t)ot * C_DIM;
            double bd = 1e300; int bi = 0x7fffffff;
            for (int k = tid; k < K_CODES; k += 256) {
                const float* crow = cbh32 + (size_t)k * C_DIM;
                double cxa = 0, cxb = 0, da = 0, db = 0;
                for (int c = 0; c < C_DIM; c += 2) {
                    double cv0 = crow[c],     tv0 = trw[c];
                    double cv1 = crow[c + 1], tv1 = trw[c + 1];
                    cxa = fma(cv0, cv0, cxa); da = fma(tv0, cv0, da);
                    cxb = fma(cv1, cv1, cxb); db = fma(tv1, cv1, db);
                }
                double d = (cxa + cxb) - 2.0 * (da + db);
                if (d < bd || (d == bd && k < bi)) { bd = d; bi = k; }
            }
            for (int off = 1; off <= 32; off <<= 1) {
                double od = __shfl_xor(bd, off);
                int    oi = __shfl_xor(bi, off);
                if (od < bd || (od == bd && oi < bi)) { bd = od; bi = oi; }
            }
            if (lane == 0) { eD[w] = bd; eI[w] = bi; }
            __syncthreads();
            if (tid == 0) {
                double b2 = eD[0]; int i2 = eI[0];
                for (int q = 1; q < 4; ++q) {
                    if (eD[q] < b2 || (eD[q] == b2 && eI[q] < i2)) { b2 = eD[q]; i2 = eI[q]; }
                }
                winner[ot] = i2;
            }
            __syncthreads();
        }
    }

    // ---- residual update: t -= cb[winner] (fp32, matches reference) ----
    for (int i = tid; i < 64 * C_DIM; i += 256) {
        const int tok = i >> 7, c = i & 127;
        th[(size_t)tok * C_DIM + c] -= cbh32[(size_t)winner[tok] * C_DIM + c];
    }
    __syncthreads();
}

// All 8 stages in one kernel — residual chain is per-token independent.
__global__ __launch_bounds__(256, 2)
void kc_all(const float* __restrict__ cb32, const _Float16* __restrict__ cb16,
            const float* __restrict__ cn, float* __restrict__ t) {
    const int h  = blockIdx.x & 7;               // XCD-affine head mapping
    const int n0 = (blockIdx.x >> 3) << 6;
    float* th = t + ((size_t)h * N_TOK + n0) * C_DIM;
#pragma unroll 1
    for (int r = 0; r < R_STAGES; ++r) {
        const size_t off = (size_t)(r * H_HEADS + h) * K_CODES;
        stage_body(cb32 + off * C_DIM, cb16 + off * C_DIM, cn + off, th);
    }
}

// Single-stage variant (used when ws can't hold the full fp16 codebook).
__global__ __launch_bounds__(256, 2)
void kc_stage_one(const float* __restrict__ cb32, const _Float16* __restrict__ cb16,
                  const float* __restrict__ cn, float* __restrict__ t) {
    const int h  = blockIdx.x & 7;
    const int n0 = (blockIdx.x >> 3) << 6;
    float* th = t + ((size_t)h * N_TOK + n0) * C_DIM;
    const size_t off = (size_t)h * K_CODES;
    stage_body(cb32 + off * C_DIM, cb16 + off * C_DIM, cn + off, th);
}

__global__ void kc_out(const float* __restrict__ x, const float* __restrict__ t,
                       const float* __restrict__ ps, float* __restrict__ out) {
    int n = blockIdx.x;
    float p = ps[n];
    const float* xr = x + (size_t)n * FEAT;
    for (int i = threadIdx.x; i < FEAT; i += 256) {
        int c = i & 127;
        float v = xr[(i & ~127) + ((c & 1) << 6) + (c >> 1)];
        float t0 = v / p;
        float tf = t[((size_t)(i >> 7) * N_TOK + n) * C_DIM + c];
        out[(size_t)n * FEAT + i] = (t0 - tf) * p;
    }
}

extern "C" void kernel_launch(void* const* d_in, const int* in_sizes, int n_in,
                              void* d_out, int out_size, void* d_ws, size_t ws_size,
                              hipStream_t stream) {
    const float* x  = (const float*)d_in[0];
    const float* cb = (const float*)d_in[1];
    float* out = (float*)d_out;

    float*    t    = (float*)d_ws;
    float*    ps   = (float*)((char*)d_ws + 16777216);
    float*    cn   = (float*)((char*)d_ws + 16793600);
    _Float16* cb16 = (_Float16*)((char*)d_ws + 17842176);

    const bool full = (ws_size >= 84951040ull);   // 17,842,176 + 67,108,864

    kc_prep<<<N_TOK, 256, 0, stream>>>(x, t, ps);

    if (full) {
        kc_cvtn<<<(R_STAGES * H_HEADS * K_CODES) / 4, 256, 0, stream>>>(cb, cb16, cn);
        kc_all<<<H_HEADS * (N_TOK / 64), 256, 0, stream>>>(cb, cb16, cn, t);
    } else {
        for (int r = 0; r < R_STAGES; ++r) {
            kc_cvtn<<<(H_HEADS * K_CODES) / 4, 256, 0, stream>>>(
                cb + (size_t)r * HKC, cb16, cn + (size_t)r * H_HEADS * K_CODES);
            kc_stage_one<<<H_HEADS * (N_TOK / 64), 256, 0, stream>>>(
                cb + (size_t)r * HKC, cb16, cn + (size_t)r * H_HEADS * K_CODES, t);
        }
    }

    kc_out<<<N_TOK, 256, 0, stream>>>(x, t, ps, out);
}